// Round 1
// baseline (970.357 us; speedup 1.0000x reference)
//
#include <hip/hip_runtime.h>

typedef _Float16 half8 __attribute__((ext_vector_type(8)));
typedef float fx4 __attribute__((ext_vector_type(4)));

#define MFMA16(a,b,c) __builtin_amdgcn_mfma_f32_16x16x32_f16(a,b,c,0,0,0)

#define BN 4
#define CC 512
#define HH 56
#define WW 56
#define NQ 3136
#define OQ 784
#define NH 8
#define HD 64

__device__ inline half8 h8z() {
    half8 v;
#pragma unroll
    for (int j = 0; j < 8; j++) v[j] = (_Float16)0.f;
    return v;
}

// ---- convert fp32 -> fp16 -------------------------------------------------
__global__ void cvt_kernel(const float* __restrict__ s, _Float16* __restrict__ d, int n) {
    int i = blockIdx.x * 256 + threadIdx.x;
    if (i < n) d[i] = (_Float16)s[i];
}

// ---- x (B,C,H*W) -> xf16 (B, NQ, C) fp16 (tiled transpose) ---------------
__global__ void xpose_kernel(const float* __restrict__ x, _Float16* __restrict__ xf) {
    __shared__ float t[32][33];
    int n0 = blockIdx.x * 32, c0 = blockIdx.y * 32, b = blockIdx.z;
    int tx = threadIdx.x, ty = threadIdx.y;
#pragma unroll
    for (int i = 0; i < 4; i++)
        t[ty + 8 * i][tx] = x[((size_t)(b * CC) + c0 + ty + 8 * i) * NQ + n0 + tx];
    __syncthreads();
#pragma unroll
    for (int i = 0; i < 4; i++)
        xf[((size_t)(b * NQ) + n0 + ty + 8 * i) * CC + c0 + tx] = (_Float16)t[tx][ty + 8 * i];
}

// ---- depthwise conv 3x3 s2 p1 + bias -> xsc (B, OQ, C) fp32 --------------
__global__ void dw_kernel(const float* __restrict__ x, const float* __restrict__ w,
                          const float* __restrict__ bias, float* __restrict__ xsc) {
    // grid (32 cb, 28 oy, 4 b), block (28, 16)
    int cb = blockIdx.x, oy = blockIdx.y, b = blockIdx.z;
    int tx = threadIdx.x, ty = threadIdx.y;
    int c = cb * 16 + ty;
    float a = bias[c];
    const float* xp = x + ((size_t)(b * CC + c) * HH) * WW;
#pragma unroll
    for (int ky = 0; ky < 3; ky++) {
        int iy = 2 * oy - 1 + ky;
        if (iy < 0 || iy >= HH) continue;
#pragma unroll
        for (int kx = 0; kx < 3; kx++) {
            int ix = 2 * tx - 1 + kx;
            if (ix < 0 || ix >= WW) continue;
            a += xp[iy * WW + ix] * w[c * 9 + ky * 3 + kx];
        }
    }
    __shared__ float tile[28][17];
    tile[tx][ty] = a;
    __syncthreads();
    int lin = ty * 28 + tx;
    int oi = lin >> 4, ci = lin & 15;
    xsc[((size_t)(b * OQ) + oy * 28 + oi) * CC + cb * 16 + ci] = tile[oi][ci];
}

// ---- LayerNorm over C -> xs16 (B*OQ, C) fp16 -----------------------------
__global__ __launch_bounds__(256) void ln_kernel(const float* __restrict__ xsc,
        const float* __restrict__ g, const float* __restrict__ bb,
        _Float16* __restrict__ xs16) {
    int row = blockIdx.x;  // b*784+o
    const float* rp = xsc + (size_t)row * CC;
    int t = threadIdx.x;
    float v0 = rp[t], v1 = rp[t + 256];
    float s = v0 + v1, ss = v0 * v0 + v1 * v1;
#pragma unroll
    for (int m = 1; m < 64; m <<= 1) {
        s += __shfl_xor(s, m, 64);
        ss += __shfl_xor(ss, m, 64);
    }
    __shared__ float red[8];
    int wv = t >> 6;
    if ((t & 63) == 0) { red[wv] = s; red[4 + wv] = ss; }
    __syncthreads();
    s = red[0] + red[1] + red[2] + red[3];
    ss = red[4] + red[5] + red[6] + red[7];
    float mean = s * (1.f / 512.f);
    float var = ss * (1.f / 512.f) - mean * mean;
    float rs = rsqrtf(var + 1e-5f);
    xs16[(size_t)row * CC + t] = (_Float16)((v0 - mean) * rs * g[t] + bb[t]);
    xs16[(size_t)row * CC + t + 256] = (_Float16)((v1 - mean) * rs * g[t + 256] + bb[t + 256]);
}

// ---- generic NT GEMM, K=512, out fp16 (M x 512) --------------------------
__global__ __launch_bounds__(256) void gemm_nt_f16(const _Float16* __restrict__ A,
        const _Float16* __restrict__ Bm, _Float16* __restrict__ O, int M) {
    __shared__ _Float16 As[128 * 72];
    __shared__ _Float16 Bs[128 * 72];
    const int m0 = blockIdx.x * 128, n0 = blockIdx.y * 128;
    const int tid = threadIdx.x;
    const int lane = tid & 63, wv = tid >> 6;
    const int wm = (wv >> 1) * 64, wn = (wv & 1) * 64;
    const int l15 = lane & 15, quad = lane >> 4;
    fx4 acc[4][4];
#pragma unroll
    for (int i = 0; i < 4; i++)
#pragma unroll
        for (int j = 0; j < 4; j++) acc[i][j] = fx4{0.f, 0.f, 0.f, 0.f};
    for (int k0 = 0; k0 < 512; k0 += 64) {
        __syncthreads();
#pragma unroll
        for (int i = 0; i < 4; i++) {
            int id = tid + 256 * i;
            int r = id >> 3, kc = (id & 7) << 3;
            int row = m0 + r;
            half8 va;
            if (row < M) va = *(const half8*)(A + (size_t)row * 512 + k0 + kc);
            else va = h8z();
            *(half8*)(As + r * 72 + kc) = va;
            *(half8*)(Bs + r * 72 + kc) = *(const half8*)(Bm + (size_t)(n0 + r) * 512 + k0 + kc);
        }
        __syncthreads();
#pragma unroll
        for (int ks = 0; ks < 2; ks++) {
            half8 af[4], bf[4];
#pragma unroll
            for (int s = 0; s < 4; s++) {
                af[s] = *(const half8*)(As + (wm + s * 16 + l15) * 72 + ks * 32 + quad * 8);
                bf[s] = *(const half8*)(Bs + (wn + s * 16 + l15) * 72 + ks * 32 + quad * 8);
            }
#pragma unroll
            for (int i = 0; i < 4; i++)
#pragma unroll
                for (int j = 0; j < 4; j++)
                    acc[i][j] = MFMA16(af[i], bf[j], acc[i][j]);
        }
    }
#pragma unroll
    for (int i = 0; i < 4; i++)
#pragma unroll
        for (int j = 0; j < 4; j++) {
            int col = n0 + wn + j * 16 + l15;
#pragma unroll
            for (int e = 0; e < 4; e++) {
                int row = m0 + wm + i * 16 + quad * 4 + e;
                if (row < M) O[(size_t)row * 512 + col] = (_Float16)acc[i][j][e];
            }
        }
}

// ---- proj GEMM: M=channels(512), N=n(3136) per b, fused bias, fp32 out ---
__global__ __launch_bounds__(256) void gemm_proj(const _Float16* __restrict__ A,
        const _Float16* __restrict__ Ball, const float* __restrict__ bias,
        float* __restrict__ Oall) {
    __shared__ _Float16 As[128 * 72];
    __shared__ _Float16 Bs[128 * 72];
    const int b = blockIdx.z;
    const _Float16* Bm = Ball + (size_t)b * NQ * 512;
    float* O = Oall + (size_t)b * CC * NQ;
    const int m0 = blockIdx.x * 128, n0 = blockIdx.y * 128;
    const int tid = threadIdx.x;
    const int lane = tid & 63, wv = tid >> 6;
    const int wm = (wv >> 1) * 64, wn = (wv & 1) * 64;
    const int l15 = lane & 15, quad = lane >> 4;
    fx4 acc[4][4];
#pragma unroll
    for (int i = 0; i < 4; i++)
#pragma unroll
        for (int j = 0; j < 4; j++) acc[i][j] = fx4{0.f, 0.f, 0.f, 0.f};
    for (int k0 = 0; k0 < 512; k0 += 64) {
        __syncthreads();
#pragma unroll
        for (int i = 0; i < 4; i++) {
            int id = tid + 256 * i;
            int r = id >> 3, kc = (id & 7) << 3;
            *(half8*)(As + r * 72 + kc) = *(const half8*)(A + (size_t)(m0 + r) * 512 + k0 + kc);
            int rowb = n0 + r;
            half8 vb;
            if (rowb < NQ) vb = *(const half8*)(Bm + (size_t)rowb * 512 + k0 + kc);
            else vb = h8z();
            *(half8*)(Bs + r * 72 + kc) = vb;
        }
        __syncthreads();
#pragma unroll
        for (int ks = 0; ks < 2; ks++) {
            half8 af[4], bf[4];
#pragma unroll
            for (int s = 0; s < 4; s++) {
                af[s] = *(const half8*)(As + (wm + s * 16 + l15) * 72 + ks * 32 + quad * 8);
                bf[s] = *(const half8*)(Bs + (wn + s * 16 + l15) * 72 + ks * 32 + quad * 8);
            }
#pragma unroll
            for (int i = 0; i < 4; i++)
#pragma unroll
                for (int j = 0; j < 4; j++)
                    acc[i][j] = MFMA16(af[i], bf[j], acc[i][j]);
        }
    }
#pragma unroll
    for (int i = 0; i < 4; i++)
#pragma unroll
        for (int j = 0; j < 4; j++) {
            int col = n0 + wn + j * 16 + l15;
            if (col < NQ) {
#pragma unroll
                for (int e = 0; e < 4; e++) {
                    int row = m0 + wm + i * 16 + quad * 4 + e;
                    O[(size_t)row * NQ + col] = acc[i][j][e] + bias[row];
                }
            }
        }
}

// ---- v16 (B,OQ,C) -> vT (B,NH,HD,OQ) -------------------------------------
__global__ void vx_kernel(const _Float16* __restrict__ v16, _Float16* __restrict__ vT) {
    int i = blockIdx.x * 256 + threadIdx.x;  // over 4*784*512
    int c = i & 511;
    int o = (i >> 9) % OQ;
    int b = i / (512 * OQ);
    vT[((size_t)(b * NH + (c >> 6)) * HD + (c & 63)) * OQ + o] = v16[i];
}

// ---- QK^T + head-mix + logit write + online Z / sum(E^2) -----------------
// grid (196 nblk, 7 oseg, 4 b), block 64
__global__ __launch_bounds__(64) void qk_mix(const _Float16* __restrict__ q16,
        const _Float16* __restrict__ k16, const float* __restrict__ tcw,
        const float* __restrict__ tcb, _Float16* __restrict__ L,
        float* __restrict__ Zp, float* __restrict__ E2p) {
    __shared__ _Float16 kl[16 * 520];
    __shared__ float tcs[64];
    __shared__ float tbb[8];
    const int b = blockIdx.z, n0 = blockIdx.x * 16, ob = blockIdx.y * 112;
    const int lane = threadIdx.x, l15 = lane & 15, quad = lane >> 4;
    tcs[lane] = tcw[lane] * 0.125f;  // fold scale = hd^-0.5 = 1/8
    if (lane < 8) tbb[lane] = tcb[lane];

    half8 aF[8][2];
    const _Float16* qrow = q16 + ((size_t)(b * NQ + n0 + l15)) * 512;
#pragma unroll
    for (int h = 0; h < 8; h++)
#pragma unroll
        for (int ks = 0; ks < 2; ks++)
            aF[h][ks] = *(const half8*)(qrow + h * 64 + ks * 32 + quad * 8);

    float z[8][4], s2[8][4];
#pragma unroll
    for (int g = 0; g < 8; g++)
#pragma unroll
        for (int e = 0; e < 4; e++) { z[g][e] = 0.f; s2[g][e] = 0.f; }
    __syncthreads();

    for (int ot = 0; ot < 7; ot++) {
        int o0 = ob + ot * 16;
        __syncthreads();
        const _Float16* kb = k16 + ((size_t)(b * OQ + o0)) * 512;
#pragma unroll
        for (int r = 0; r < 16; r++)
            *(half8*)(kl + r * 520 + lane * 8) = *(const half8*)(kb + (size_t)r * 512 + lane * 8);
        __syncthreads();
        fx4 s[8];
#pragma unroll
        for (int h = 0; h < 8; h++) {
            fx4 a = fx4{0.f, 0.f, 0.f, 0.f};
#pragma unroll
            for (int ks = 0; ks < 2; ks++) {
                half8 bF = *(const half8*)(kl + l15 * 520 + h * 64 + ks * 32 + quad * 8);
                a = MFMA16(aF[h][ks], bF, a);
            }
            s[h] = a;
        }
#pragma unroll
        for (int g = 0; g < 8; g++) {
#pragma unroll
            for (int e = 0; e < 4; e++) {
                float v = tbb[g];
#pragma unroll
                for (int h = 0; h < 8; h++) v += tcs[g * 8 + h] * s[h][e];
                _Float16 vh = (_Float16)v;
                float vr = (float)vh;            // use rounded value so Z matches pass 2 exactly
                float ex = __expf(vr);
                z[g][e] += ex;
                s2[g][e] += ex * ex;
                L[((size_t)((b * 8 + g) * NQ) + n0 + quad * 4 + e) * OQ + o0 + l15] = vh;
            }
        }
    }
    // reduce partials over the 16 lanes (o-columns) of each quad group
#pragma unroll
    for (int m = 1; m < 16; m <<= 1) {
#pragma unroll
        for (int g = 0; g < 8; g++)
#pragma unroll
            for (int e = 0; e < 4; e++) {
                z[g][e] += __shfl_xor(z[g][e], m, 64);
                s2[g][e] += __shfl_xor(s2[g][e], m, 64);
            }
    }
    if (l15 < 8) {
        int g = l15;
#pragma unroll
        for (int e = 0; e < 4; e++) {
            atomicAdd(&Zp[(b * 8 + g) * NQ + n0 + quad * 4 + e], z[g][e]);
            atomicAdd(&E2p[(b * 8 + g) * NQ + n0 + quad * 4 + e], s2[g][e]);
        }
    }
}

// ---- per-row finalize: Zinv, and sum of P^2 into S2[b,g] -----------------
__global__ __launch_bounds__(256) void zfin_kernel(const float* __restrict__ Zp,
        const float* __restrict__ E2p, float* __restrict__ Zinv, float* __restrict__ S2) {
    int i = blockIdx.x * 256 + threadIdx.x;  // 0 .. 4*8*3136-1
    float zi = 1.f / Zp[i];
    Zinv[i] = zi;
    float r = E2p[i] * zi * zi;
#pragma unroll
    for (int m = 1; m < 64; m <<= 1) r += __shfl_xor(r, m, 64);
    if ((threadIdx.x & 63) == 0) atomicAdd(&S2[i / NQ], r);
}

// ---- instance-norm scalars ------------------------------------------------
__global__ void rfin_kernel(const float* __restrict__ S2, float* __restrict__ R,
                            float* __restrict__ RM) {
    int t = threadIdx.x;
    if (t < 32) {
        const float mm = 1.f / (float)OQ;
        float mean2 = S2[t] * (1.f / ((float)NQ * (float)OQ));
        float var = mean2 - mm * mm;
        float rv = rsqrtf(var + 1e-5f);
        R[t] = rv;
        RM[t] = rv * mm;
    }
}

// ---- pass 2: softmax-normalize + instnorm + *W + PV ----------------------
// grid (196 nblk, 2 ghalf, 4 b), block 64
__global__ __launch_bounds__(64) void pv_kernel(const _Float16* __restrict__ L,
        const float* __restrict__ W, const _Float16* __restrict__ vT,
        const float* __restrict__ Zinv, const float* __restrict__ R,
        const float* __restrict__ RM, _Float16* __restrict__ outp) {
    const int b = blockIdx.z, n0 = blockIdx.x * 16, gh = blockIdx.y * 4;
    const int lane = threadIdx.x, l15 = lane & 15, quad = lane >> 4;
    float czr[4], rm4[4];
#pragma unroll
    for (int g = 0; g < 4; g++) {
        int bg = b * 8 + gh + g;
        czr[g] = Zinv[bg * NQ + n0 + l15] * R[bg];
        rm4[g] = RM[bg];
    }
    fx4 acc[4][4];
#pragma unroll
    for (int g = 0; g < 4; g++)
#pragma unroll
        for (int d = 0; d < 4; d++) acc[g][d] = fx4{0.f, 0.f, 0.f, 0.f};

    for (int oc = 0; oc < 25; oc++) {
        int kbase = oc * 32 + quad * 8;
        bool valid = kbase < OQ;  // tail chunk: quads 2,3 off (784 = 24*32+16)
#pragma unroll
        for (int g = 0; g < 4; g++) {
            int bg = b * 8 + gh + g;
            half8 aH = h8z();
            if (valid) {
                size_t base = ((size_t)bg * NQ + n0 + l15) * OQ + kbase;
                half8 l8 = *(const half8*)(L + base);
                fx4 w0 = *(const fx4*)(W + base);
                fx4 w1 = *(const fx4*)(W + base + 4);
#pragma unroll
                for (int j = 0; j < 8; j++) {
                    float e = __expf((float)l8[j]);
                    float a = e * czr[g] - rm4[g];
                    float wv = (j < 4) ? w0[j] : w1[j - 4];
                    aH[j] = (_Float16)(a * wv);
                }
            }
#pragma unroll
            for (int ds = 0; ds < 4; ds++) {
                half8 bF = h8z();
                if (valid)
                    bF = *(const half8*)(vT + ((size_t)bg * HD + ds * 16 + l15) * OQ + kbase);
                acc[g][ds] = MFMA16(aH, bF, acc[g][ds]);
            }
        }
    }
#pragma unroll
    for (int g = 0; g < 4; g++)
#pragma unroll
        for (int ds = 0; ds < 4; ds++)
#pragma unroll
            for (int e = 0; e < 4; e++) {
                int n = n0 + quad * 4 + e;
                int c = (gh + g) * 64 + ds * 16 + l15;
                outp[((size_t)b * NQ + n) * 512 + c] = (_Float16)acc[g][ds][e];
            }
}

extern "C" void kernel_launch(void* const* d_in, const int* in_sizes, int n_in,
                              void* d_out, int out_size, void* d_ws, size_t ws_size,
                              hipStream_t stream) {
    const float* x = (const float*)d_in[0];
    const float* aw = (const float*)d_in[1];
    const float* q_w = (const float*)d_in[2];
    const float* k_w = (const float*)d_in[3];
    const float* v_w = (const float*)d_in[4];
    const float* sr_w = (const float*)d_in[5];
    const float* sr_b = (const float*)d_in[6];
    const float* ln_g = (const float*)d_in[7];
    const float* ln_b = (const float*)d_in[8];
    const float* tc_w = (const float*)d_in[9];
    const float* tc_b = (const float*)d_in[10];
    const float* p_w = (const float*)d_in[11];
    const float* p_b = (const float*)d_in[12];
    float* out = (float*)d_out;

    char* p = (char*)d_ws;
    auto take = [&](size_t bytes) -> char* {
        char* r = p;
        p += (bytes + 255) & ~(size_t)255;
        return r;
    };
    _Float16* qw16 = (_Float16*)take(512 * 512 * 2);
    _Float16* kw16 = (_Float16*)take(512 * 512 * 2);
    _Float16* vw16 = (_Float16*)take(512 * 512 * 2);
    _Float16* pw16 = (_Float16*)take(512 * 512 * 2);
    _Float16* xf16 = (_Float16*)take((size_t)BN * NQ * CC * 2);
    float* xsc = (float*)take((size_t)BN * OQ * CC * 4);
    _Float16* xs16 = (_Float16*)take((size_t)BN * OQ * CC * 2);
    _Float16* q16 = (_Float16*)take((size_t)BN * NQ * CC * 2);
    _Float16* k16 = (_Float16*)take((size_t)BN * OQ * CC * 2);
    _Float16* v16 = (_Float16*)take((size_t)BN * OQ * CC * 2);
    _Float16* vT = (_Float16*)take((size_t)BN * OQ * CC * 2);
    _Float16* outp = (_Float16*)take((size_t)BN * NQ * CC * 2);
    float* Zp = (float*)take((size_t)BN * NH * NQ * 4);
    float* E2p = (float*)take((size_t)BN * NH * NQ * 4);
    float* S2 = (float*)take(32 * 4);
    float* Rv = (float*)take(32 * 4);
    float* RM = (float*)take(32 * 4);
    float* Zinv = (float*)take((size_t)BN * NH * NQ * 4);
    _Float16* L = (_Float16*)take((size_t)BN * NH * NQ * OQ * 2);

    // weights to fp16
    cvt_kernel<<<1024, 256, 0, stream>>>(q_w, qw16, 512 * 512);
    cvt_kernel<<<1024, 256, 0, stream>>>(k_w, kw16, 512 * 512);
    cvt_kernel<<<1024, 256, 0, stream>>>(v_w, vw16, 512 * 512);
    cvt_kernel<<<1024, 256, 0, stream>>>(p_w, pw16, 512 * 512);
    // x transpose to (B,NQ,C) fp16
    xpose_kernel<<<dim3(98, 16, BN), dim3(32, 8), 0, stream>>>(x, xf16);
    // spatial reduction conv + LN
    dw_kernel<<<dim3(32, 28, BN), dim3(28, 16), 0, stream>>>(x, sr_w, sr_b, xsc);
    ln_kernel<<<BN * OQ, 256, 0, stream>>>(xsc, ln_g, ln_b, xs16);
    // q / k / v projections
    gemm_nt_f16<<<dim3(98, 4), 256, 0, stream>>>(xf16, qw16, q16, BN * NQ);
    gemm_nt_f16<<<dim3(25, 4), 256, 0, stream>>>(xs16, kw16, k16, BN * OQ);
    gemm_nt_f16<<<dim3(25, 4), 256, 0, stream>>>(xs16, vw16, v16, BN * OQ);
    vx_kernel<<<(BN * OQ * CC) / 256, 256, 0, stream>>>(v16, vT);
    // zero accumulators (Zp, E2p, S2 are contiguous)
    hipMemsetAsync(Zp, 0, ((char*)S2 - (char*)Zp) + 256, stream);
    // phase 1: logits + online softmax stats
    qk_mix<<<dim3(196, 7, BN), 64, 0, stream>>>(q16, k16, tc_w, tc_b, L, Zp, E2p);
    zfin_kernel<<<(BN * NH * NQ) / 256, 256, 0, stream>>>(Zp, E2p, Zinv, S2);
    rfin_kernel<<<1, 64, 0, stream>>>(S2, Rv, RM);
    // phase 2: normalize + instnorm + attn_weights + PV
    pv_kernel<<<dim3(196, 2, BN), 64, 0, stream>>>(L, aw, vT, Zinv, Rv, RM, outp);
    // output projection + bias, written directly in (B,C,H,W)
    gemm_proj<<<dim3(4, 25, BN), 256, 0, stream>>>(pw16, outp, p_b, out);
}

// Round 2
// 875.514 us; speedup vs baseline: 1.1083x; 1.1083x over previous
//
#include <hip/hip_runtime.h>

typedef _Float16 half8 __attribute__((ext_vector_type(8)));
typedef _Float16 half4 __attribute__((ext_vector_type(4)));
typedef float fx4 __attribute__((ext_vector_type(4)));

#define MFMA16(a,b,c) __builtin_amdgcn_mfma_f32_16x16x32_f16(a,b,c,0,0,0)

#define BN 4
#define CC 512
#define HH 56
#define WW 56
#define NQ 3136
#define OQ 784
#define NH 8
#define HD 64

__device__ inline half8 h8z() {
    half8 v;
#pragma unroll
    for (int j = 0; j < 8; j++) v[j] = (_Float16)0.f;
    return v;
}

// ---- convert 4 fp32 weight mats -> fp16 (contiguous dsts) ----------------
__global__ void cvt4_kernel(const float* __restrict__ a, const float* __restrict__ b,
                            const float* __restrict__ c, const float* __restrict__ d,
                            _Float16* __restrict__ o) {
    int y = blockIdx.y;
    const float* s = (y == 0) ? a : (y == 1) ? b : (y == 2) ? c : d;
    int i = blockIdx.x * 256 + threadIdx.x;
    o[(size_t)y * 262144 + i] = (_Float16)s[i];
}

// ---- x (B,C,H*W) -> xf16 (B, NQ, C) fp16 (tiled transpose) ---------------
__global__ void xpose_kernel(const float* __restrict__ x, _Float16* __restrict__ xf) {
    __shared__ float t[32][33];
    int n0 = blockIdx.x * 32, c0 = blockIdx.y * 32, b = blockIdx.z;
    int tx = threadIdx.x, ty = threadIdx.y;
#pragma unroll
    for (int i = 0; i < 4; i++)
        t[ty + 8 * i][tx] = x[((size_t)(b * CC) + c0 + ty + 8 * i) * NQ + n0 + tx];
    __syncthreads();
#pragma unroll
    for (int i = 0; i < 4; i++)
        xf[((size_t)(b * NQ) + n0 + ty + 8 * i) * CC + c0 + tx] = (_Float16)t[tx][ty + 8 * i];
}

// ---- depthwise conv 3x3 s2 p1 + bias -> xsc (B, OQ, C) fp32 --------------
__global__ void dw_kernel(const float* __restrict__ x, const float* __restrict__ w,
                          const float* __restrict__ bias, float* __restrict__ xsc) {
    int cb = blockIdx.x, oy = blockIdx.y, b = blockIdx.z;
    int tx = threadIdx.x, ty = threadIdx.y;
    int c = cb * 16 + ty;
    float a = bias[c];
    const float* xp = x + ((size_t)(b * CC + c) * HH) * WW;
#pragma unroll
    for (int ky = 0; ky < 3; ky++) {
        int iy = 2 * oy - 1 + ky;
        if (iy < 0 || iy >= HH) continue;
#pragma unroll
        for (int kx = 0; kx < 3; kx++) {
            int ix = 2 * tx - 1 + kx;
            if (ix < 0 || ix >= WW) continue;
            a += xp[iy * WW + ix] * w[c * 9 + ky * 3 + kx];
        }
    }
    __shared__ float tile[28][17];
    tile[tx][ty] = a;
    __syncthreads();
    int lin = ty * 28 + tx;
    int oi = lin >> 4, ci = lin & 15;
    xsc[((size_t)(b * OQ) + oy * 28 + oi) * CC + cb * 16 + ci] = tile[oi][ci];
}

// ---- LayerNorm over C -> xs16 (B*OQ, C) fp16 -----------------------------
__global__ __launch_bounds__(256) void ln_kernel(const float* __restrict__ xsc,
        const float* __restrict__ g, const float* __restrict__ bb,
        _Float16* __restrict__ xs16) {
    int row = blockIdx.x;
    const float* rp = xsc + (size_t)row * CC;
    int t = threadIdx.x;
    float v0 = rp[t], v1 = rp[t + 256];
    float s = v0 + v1, ss = v0 * v0 + v1 * v1;
#pragma unroll
    for (int m = 1; m < 64; m <<= 1) {
        s += __shfl_xor(s, m, 64);
        ss += __shfl_xor(ss, m, 64);
    }
    __shared__ float red[8];
    int wv = t >> 6;
    if ((t & 63) == 0) { red[wv] = s; red[4 + wv] = ss; }
    __syncthreads();
    s = red[0] + red[1] + red[2] + red[3];
    ss = red[4] + red[5] + red[6] + red[7];
    float mean = s * (1.f / 512.f);
    float var = ss * (1.f / 512.f) - mean * mean;
    float rs = rsqrtf(var + 1e-5f);
    xs16[(size_t)row * CC + t] = (_Float16)((v0 - mean) * rs * g[t] + bb[t]);
    xs16[(size_t)row * CC + t + 256] = (_Float16)((v1 - mean) * rs * g[t + 256] + bb[t + 256]);
}

// ---- generic NT GEMM, K=512, out fp16 (M x 512) (used for q) -------------
__global__ __launch_bounds__(256) void gemm_nt_f16(const _Float16* __restrict__ A,
        const _Float16* __restrict__ Bm, _Float16* __restrict__ O, int M) {
    __shared__ _Float16 As[128 * 72];
    __shared__ _Float16 Bs[128 * 72];
    const int m0 = blockIdx.x * 128, n0 = blockIdx.y * 128;
    const int tid = threadIdx.x;
    const int lane = tid & 63, wv = tid >> 6;
    const int wm = (wv >> 1) * 64, wn = (wv & 1) * 64;
    const int l15 = lane & 15, quad = lane >> 4;
    fx4 acc[4][4];
#pragma unroll
    for (int i = 0; i < 4; i++)
#pragma unroll
        for (int j = 0; j < 4; j++) acc[i][j] = fx4{0.f, 0.f, 0.f, 0.f};
    for (int k0 = 0; k0 < 512; k0 += 64) {
        __syncthreads();
#pragma unroll
        for (int i = 0; i < 4; i++) {
            int id = tid + 256 * i;
            int r = id >> 3, kc = (id & 7) << 3;
            int row = m0 + r;
            half8 va;
            if (row < M) va = *(const half8*)(A + (size_t)row * 512 + k0 + kc);
            else va = h8z();
            *(half8*)(As + r * 72 + kc) = va;
            *(half8*)(Bs + r * 72 + kc) = *(const half8*)(Bm + (size_t)(n0 + r) * 512 + k0 + kc);
        }
        __syncthreads();
#pragma unroll
        for (int ks = 0; ks < 2; ks++) {
            half8 af[4], bf[4];
#pragma unroll
            for (int s = 0; s < 4; s++) {
                af[s] = *(const half8*)(As + (wm + s * 16 + l15) * 72 + ks * 32 + quad * 8);
                bf[s] = *(const half8*)(Bs + (wn + s * 16 + l15) * 72 + ks * 32 + quad * 8);
            }
#pragma unroll
            for (int i = 0; i < 4; i++)
#pragma unroll
                for (int j = 0; j < 4; j++)
                    acc[i][j] = MFMA16(af[i], bf[j], acc[i][j]);
        }
    }
#pragma unroll
    for (int i = 0; i < 4; i++)
#pragma unroll
        for (int j = 0; j < 4; j++) {
            int col = n0 + wn + j * 16 + l15;
#pragma unroll
            for (int e = 0; e < 4; e++) {
                int row = m0 + wm + i * 16 + quad * 4 + e;
                if (row < M) O[(size_t)row * 512 + col] = (_Float16)acc[i][j][e];
            }
        }
}

// ---- fused k+v GEMM: z=0 -> k16 (B*OQ,512); z=1 -> vT (B,NH,HD,OQ) -------
__global__ __launch_bounds__(256) void gemm_kv(const _Float16* __restrict__ A,
        const _Float16* __restrict__ kw, const _Float16* __restrict__ vw,
        _Float16* __restrict__ k16, _Float16* __restrict__ vT) {
    __shared__ _Float16 As[128 * 72];
    __shared__ _Float16 Bs[128 * 72];
    const int m0 = blockIdx.x * 128, n0 = blockIdx.y * 128;
    const int isv = blockIdx.z;
    const _Float16* Bm = isv ? vw : kw;
    const int M = BN * OQ;
    const int tid = threadIdx.x;
    const int lane = tid & 63, wv = tid >> 6;
    const int wm = (wv >> 1) * 64, wn = (wv & 1) * 64;
    const int l15 = lane & 15, quad = lane >> 4;
    fx4 acc[4][4];
#pragma unroll
    for (int i = 0; i < 4; i++)
#pragma unroll
        for (int j = 0; j < 4; j++) acc[i][j] = fx4{0.f, 0.f, 0.f, 0.f};
    for (int k0 = 0; k0 < 512; k0 += 64) {
        __syncthreads();
#pragma unroll
        for (int i = 0; i < 4; i++) {
            int id = tid + 256 * i;
            int r = id >> 3, kc = (id & 7) << 3;
            int row = m0 + r;
            half8 va;
            if (row < M) va = *(const half8*)(A + (size_t)row * 512 + k0 + kc);
            else va = h8z();
            *(half8*)(As + r * 72 + kc) = va;
            *(half8*)(Bs + r * 72 + kc) = *(const half8*)(Bm + (size_t)(n0 + r) * 512 + k0 + kc);
        }
        __syncthreads();
#pragma unroll
        for (int ks = 0; ks < 2; ks++) {
            half8 af[4], bf[4];
#pragma unroll
            for (int s = 0; s < 4; s++) {
                af[s] = *(const half8*)(As + (wm + s * 16 + l15) * 72 + ks * 32 + quad * 8);
                bf[s] = *(const half8*)(Bs + (wn + s * 16 + l15) * 72 + ks * 32 + quad * 8);
            }
#pragma unroll
            for (int i = 0; i < 4; i++)
#pragma unroll
                for (int j = 0; j < 4; j++)
                    acc[i][j] = MFMA16(af[i], bf[j], acc[i][j]);
        }
    }
    if (!isv) {
#pragma unroll
        for (int i = 0; i < 4; i++)
#pragma unroll
            for (int j = 0; j < 4; j++) {
                int col = n0 + wn + j * 16 + l15;
#pragma unroll
                for (int e = 0; e < 4; e++) {
                    int row = m0 + wm + i * 16 + quad * 4 + e;
                    if (row < M) k16[(size_t)row * 512 + col] = (_Float16)acc[i][j][e];
                }
            }
    } else {
        // vT[(b*8 + c/64)*64 + c%64][o], 4 consecutive o -> packed 8B store
#pragma unroll
        for (int i = 0; i < 4; i++) {
            int row = m0 + wm + i * 16 + quad * 4;  // = b*784 + o, multiple of 4
            if (row < M) {
                int b = row / OQ;
                int o = row - b * OQ;
#pragma unroll
                for (int j = 0; j < 4; j++) {
                    int c = n0 + wn + j * 16 + l15;
                    half4 pk;
#pragma unroll
                    for (int e = 0; e < 4; e++) pk[e] = (_Float16)acc[i][j][e];
                    *(half4*)(vT + ((size_t)(b * NH + (c >> 6)) * HD + (c & 63)) * OQ + o) = pk;
                }
            }
        }
    }
}

// ---- proj GEMM: M=channels(512), N=n(3136) per b, fused bias, fp32 out ---
__global__ __launch_bounds__(256) void gemm_proj(const _Float16* __restrict__ A,
        const _Float16* __restrict__ Ball, const float* __restrict__ bias,
        float* __restrict__ Oall) {
    __shared__ _Float16 As[128 * 72];
    __shared__ _Float16 Bs[128 * 72];
    const int b = blockIdx.z;
    const _Float16* Bm = Ball + (size_t)b * NQ * 512;
    float* O = Oall + (size_t)b * CC * NQ;
    const int m0 = blockIdx.x * 128, n0 = blockIdx.y * 128;
    const int tid = threadIdx.x;
    const int lane = tid & 63, wv = tid >> 6;
    const int wm = (wv >> 1) * 64, wn = (wv & 1) * 64;
    const int l15 = lane & 15, quad = lane >> 4;
    fx4 acc[4][4];
#pragma unroll
    for (int i = 0; i < 4; i++)
#pragma unroll
        for (int j = 0; j < 4; j++) acc[i][j] = fx4{0.f, 0.f, 0.f, 0.f};
    for (int k0 = 0; k0 < 512; k0 += 64) {
        __syncthreads();
#pragma unroll
        for (int i = 0; i < 4; i++) {
            int id = tid + 256 * i;
            int r = id >> 3, kc = (id & 7) << 3;
            *(half8*)(As + r * 72 + kc) = *(const half8*)(A + (size_t)(m0 + r) * 512 + k0 + kc);
            int rowb = n0 + r;
            half8 vb;
            if (rowb < NQ) vb = *(const half8*)(Bm + (size_t)rowb * 512 + k0 + kc);
            else vb = h8z();
            *(half8*)(Bs + r * 72 + kc) = vb;
        }
        __syncthreads();
#pragma unroll
        for (int ks = 0; ks < 2; ks++) {
            half8 af[4], bf[4];
#pragma unroll
            for (int s = 0; s < 4; s++) {
                af[s] = *(const half8*)(As + (wm + s * 16 + l15) * 72 + ks * 32 + quad * 8);
                bf[s] = *(const half8*)(Bs + (wn + s * 16 + l15) * 72 + ks * 32 + quad * 8);
            }
#pragma unroll
            for (int i = 0; i < 4; i++)
#pragma unroll
                for (int j = 0; j < 4; j++)
                    acc[i][j] = MFMA16(af[i], bf[j], acc[i][j]);
        }
    }
#pragma unroll
    for (int i = 0; i < 4; i++)
#pragma unroll
        for (int j = 0; j < 4; j++) {
            int col = n0 + wn + j * 16 + l15;
            if (col < NQ) {
#pragma unroll
                for (int e = 0; e < 4; e++) {
                    int row = m0 + wm + i * 16 + quad * 4 + e;
                    O[(size_t)row * NQ + col] = acc[i][j][e] + bias[row];
                }
            }
        }
}

// ---- QK^T + head-mix + logit write + online Z / sum(E^2) -----------------
__global__ __launch_bounds__(64) void qk_mix(const _Float16* __restrict__ q16,
        const _Float16* __restrict__ k16, const float* __restrict__ tcw,
        const float* __restrict__ tcb, _Float16* __restrict__ L,
        float* __restrict__ Zp, float* __restrict__ E2p) {
    __shared__ _Float16 kl[16 * 520];
    __shared__ float tcs[64];
    __shared__ float tbb[8];
    const int b = blockIdx.z, n0 = blockIdx.x * 16, ob = blockIdx.y * 112;
    const int lane = threadIdx.x, l15 = lane & 15, quad = lane >> 4;
    tcs[lane] = tcw[lane] * 0.125f;
    if (lane < 8) tbb[lane] = tcb[lane];

    half8 aF[8][2];
    const _Float16* qrow = q16 + ((size_t)(b * NQ + n0 + l15)) * 512;
#pragma unroll
    for (int h = 0; h < 8; h++)
#pragma unroll
        for (int ks = 0; ks < 2; ks++)
            aF[h][ks] = *(const half8*)(qrow + h * 64 + ks * 32 + quad * 8);

    float z[8][4], s2[8][4];
#pragma unroll
    for (int g = 0; g < 8; g++)
#pragma unroll
        for (int e = 0; e < 4; e++) { z[g][e] = 0.f; s2[g][e] = 0.f; }
    __syncthreads();

    for (int ot = 0; ot < 7; ot++) {
        int o0 = ob + ot * 16;
        __syncthreads();
        const _Float16* kb = k16 + ((size_t)(b * OQ + o0)) * 512;
#pragma unroll
        for (int r = 0; r < 16; r++)
            *(half8*)(kl + r * 520 + lane * 8) = *(const half8*)(kb + (size_t)r * 512 + lane * 8);
        __syncthreads();
        fx4 s[8];
#pragma unroll
        for (int h = 0; h < 8; h++) {
            fx4 a = fx4{0.f, 0.f, 0.f, 0.f};
#pragma unroll
            for (int ks = 0; ks < 2; ks++) {
                half8 bF = *(const half8*)(kl + l15 * 520 + h * 64 + ks * 32 + quad * 8);
                a = MFMA16(aF[h][ks], bF, a);
            }
            s[h] = a;
        }
#pragma unroll
        for (int g = 0; g < 8; g++) {
#pragma unroll
            for (int e = 0; e < 4; e++) {
                float v = tbb[g];
#pragma unroll
                for (int h = 0; h < 8; h++) v += tcs[g * 8 + h] * s[h][e];
                _Float16 vh = (_Float16)v;
                float vr = (float)vh;
                float ex = __expf(vr);
                z[g][e] += ex;
                s2[g][e] += ex * ex;
                L[((size_t)((b * 8 + g) * NQ) + n0 + quad * 4 + e) * OQ + o0 + l15] = vh;
            }
        }
    }
#pragma unroll
    for (int m = 1; m < 16; m <<= 1) {
#pragma unroll
        for (int g = 0; g < 8; g++)
#pragma unroll
            for (int e = 0; e < 4; e++) {
                z[g][e] += __shfl_xor(z[g][e], m, 64);
                s2[g][e] += __shfl_xor(s2[g][e], m, 64);
            }
    }
    if (l15 < 8) {
        int g = l15;
#pragma unroll
        for (int e = 0; e < 4; e++) {
            atomicAdd(&Zp[(b * 8 + g) * NQ + n0 + quad * 4 + e], z[g][e]);
            atomicAdd(&E2p[(b * 8 + g) * NQ + n0 + quad * 4 + e], s2[g][e]);
        }
    }
}

// ---- per-row finalize: Zinv, and sum of P^2 into S2[b,g] -----------------
__global__ __launch_bounds__(256) void zfin_kernel(const float* __restrict__ Zp,
        const float* __restrict__ E2p, float* __restrict__ Zinv, float* __restrict__ S2) {
    int i = blockIdx.x * 256 + threadIdx.x;
    float zi = 1.f / Zp[i];
    Zinv[i] = zi;
    float r = E2p[i] * zi * zi;
#pragma unroll
    for (int m = 1; m < 64; m <<= 1) r += __shfl_xor(r, m, 64);
    if ((threadIdx.x & 63) == 0) atomicAdd(&S2[i / NQ], r);
}

// ---- instance-norm scalars ------------------------------------------------
__global__ void rfin_kernel(const float* __restrict__ S2, float* __restrict__ R,
                            float* __restrict__ RM) {
    int t = threadIdx.x;
    if (t < 32) {
        const float mm = 1.f / (float)OQ;
        float mean2 = S2[t] * (1.f / ((float)NQ * (float)OQ));
        float var = mean2 - mm * mm;
        float rv = rsqrtf(var + 1e-5f);
        R[t] = rv;
        RM[t] = rv * mm;
    }
}

// ---- pass 2: softmax-normalize + instnorm + *W + PV ----------------------
// grid (196 nblk, 8 g, 4 b), block 64  -> 24.5 waves/CU
__global__ __launch_bounds__(64) void pv_kernel(const _Float16* __restrict__ L,
        const float* __restrict__ W, const _Float16* __restrict__ vT,
        const float* __restrict__ Zinv, const float* __restrict__ R,
        const float* __restrict__ RM, _Float16* __restrict__ outp) {
    const int b = blockIdx.z, n0 = blockIdx.x * 16, g = blockIdx.y;
    const int lane = threadIdx.x, l15 = lane & 15, quad = lane >> 4;
    const int bg = b * 8 + g;
    const float czr = Zinv[bg * NQ + n0 + l15] * R[bg];
    const float rm = RM[bg];
    const _Float16* Lrow = L + ((size_t)bg * NQ + n0 + l15) * OQ;
    const float* Wrow = W + ((size_t)bg * NQ + n0 + l15) * OQ;
    const _Float16* vb = vT + (size_t)bg * HD * OQ;
    fx4 acc[4];
#pragma unroll
    for (int d = 0; d < 4; d++) acc[d] = fx4{0.f, 0.f, 0.f, 0.f};

#pragma unroll 5
    for (int oc = 0; oc < 25; oc++) {
        int kbase = oc * 32 + quad * 8;
        bool valid = kbase < OQ;  // tail chunk: quads 2,3 off (784 = 24*32+16)
        half8 aH = h8z();
        if (valid) {
            half8 l8 = *(const half8*)(Lrow + kbase);
            fx4 w0 = *(const fx4*)(Wrow + kbase);
            fx4 w1 = *(const fx4*)(Wrow + kbase + 4);
#pragma unroll
            for (int j = 0; j < 8; j++) {
                float e = __expf((float)l8[j]);
                float a = e * czr - rm;
                float wv = (j < 4) ? w0[j] : w1[j - 4];
                aH[j] = (_Float16)(a * wv);
            }
        }
#pragma unroll
        for (int ds = 0; ds < 4; ds++) {
            half8 bF = h8z();
            if (valid)
                bF = *(const half8*)(vb + ((size_t)(ds * 16 + l15)) * OQ + kbase);
            acc[ds] = MFMA16(aH, bF, acc[ds]);
        }
    }
#pragma unroll
    for (int ds = 0; ds < 4; ds++)
#pragma unroll
        for (int e = 0; e < 4; e++) {
            int n = n0 + quad * 4 + e;
            int c = g * 64 + ds * 16 + l15;
            outp[((size_t)b * NQ + n) * 512 + c] = (_Float16)acc[ds][e];
        }
}

extern "C" void kernel_launch(void* const* d_in, const int* in_sizes, int n_in,
                              void* d_out, int out_size, void* d_ws, size_t ws_size,
                              hipStream_t stream) {
    const float* x = (const float*)d_in[0];
    const float* aw = (const float*)d_in[1];
    const float* q_w = (const float*)d_in[2];
    const float* k_w = (const float*)d_in[3];
    const float* v_w = (const float*)d_in[4];
    const float* sr_w = (const float*)d_in[5];
    const float* sr_b = (const float*)d_in[6];
    const float* ln_g = (const float*)d_in[7];
    const float* ln_b = (const float*)d_in[8];
    const float* tc_w = (const float*)d_in[9];
    const float* tc_b = (const float*)d_in[10];
    const float* p_w = (const float*)d_in[11];
    const float* p_b = (const float*)d_in[12];
    float* out = (float*)d_out;

    char* p = (char*)d_ws;
    auto take = [&](size_t bytes) -> char* {
        char* r = p;
        p += (bytes + 255) & ~(size_t)255;
        return r;
    };
    _Float16* qw16 = (_Float16*)take(512 * 512 * 2);  // qw,kw,vw,pw contiguous
    _Float16* kw16 = (_Float16*)take(512 * 512 * 2);
    _Float16* vw16 = (_Float16*)take(512 * 512 * 2);
    _Float16* pw16 = (_Float16*)take(512 * 512 * 2);
    _Float16* xf16 = (_Float16*)take((size_t)BN * NQ * CC * 2);
    float* xsc = (float*)take((size_t)BN * OQ * CC * 4);
    _Float16* xs16 = (_Float16*)take((size_t)BN * OQ * CC * 2);
    _Float16* q16 = (_Float16*)take((size_t)BN * NQ * CC * 2);
    _Float16* k16 = (_Float16*)take((size_t)BN * OQ * CC * 2);
    _Float16* vT = (_Float16*)take((size_t)BN * OQ * CC * 2);
    _Float16* outp = (_Float16*)take((size_t)BN * NQ * CC * 2);
    float* Zp = (float*)take((size_t)BN * NH * NQ * 4);
    float* E2p = (float*)take((size_t)BN * NH * NQ * 4);
    float* S2 = (float*)take(32 * 4);
    float* Rv = (float*)take(32 * 4);
    float* RM = (float*)take(32 * 4);
    float* Zinv = (float*)take((size_t)BN * NH * NQ * 4);
    _Float16* L = (_Float16*)take((size_t)BN * NH * NQ * OQ * 2);

    // weights to fp16 (one launch; dsts are contiguous starting at qw16)
    cvt4_kernel<<<dim3(1024, 4), 256, 0, stream>>>(q_w, k_w, v_w, p_w, qw16);
    // x transpose to (B,NQ,C) fp16
    xpose_kernel<<<dim3(98, 16, BN), dim3(32, 8), 0, stream>>>(x, xf16);
    // spatial reduction conv + LN
    dw_kernel<<<dim3(32, 28, BN), dim3(28, 16), 0, stream>>>(x, sr_w, sr_b, xsc);
    ln_kernel<<<BN * OQ, 256, 0, stream>>>(xsc, ln_g, ln_b, xs16);
    // q projection; fused k+v projection (v written directly as vT)
    gemm_nt_f16<<<dim3(98, 4), 256, 0, stream>>>(xf16, qw16, q16, BN * NQ);
    gemm_kv<<<dim3(25, 4, 2), 256, 0, stream>>>(xs16, kw16, vw16, k16, vT);
    // zero accumulators (Zp, E2p, S2 contiguous)
    hipMemsetAsync(Zp, 0, ((char*)S2 - (char*)Zp) + 256, stream);
    // phase 1: logits + online softmax stats
    qk_mix<<<dim3(196, 7, BN), 64, 0, stream>>>(q16, k16, tc_w, tc_b, L, Zp, E2p);
    zfin_kernel<<<(BN * NH * NQ) / 256, 256, 0, stream>>>(Zp, E2p, Zinv, S2);
    rfin_kernel<<<1, 64, 0, stream>>>(S2, Rv, RM);
    // phase 2: normalize + instnorm + attn_weights + PV (1 head per wave)
    pv_kernel<<<dim3(196, 8, BN), 64, 0, stream>>>(L, aw, vT, Zinv, Rv, RM, outp);
    // output projection + bias, written directly in (B,C,H,W)
    gemm_proj<<<dim3(4, 25, BN), 256, 0, stream>>>(pw16, outp, p_b, out);
}

// Round 3
// 792.717 us; speedup vs baseline: 1.2241x; 1.1044x over previous
//
#include <hip/hip_runtime.h>

typedef _Float16 half8 __attribute__((ext_vector_type(8)));
typedef _Float16 half4 __attribute__((ext_vector_type(4)));
typedef float fx4 __attribute__((ext_vector_type(4)));

#define MFMA16(a,b,c) __builtin_amdgcn_mfma_f32_16x16x32_f16(a,b,c,0,0,0)

#define BN 4
#define CC 512
#define HH 56
#define WW 56
#define NQ 3136
#define OQ 784
#define NH 8
#define HD 64
#define NSEG 7
#define BGN (BN * NH * NQ)   // 100352

__device__ inline half8 h8z() {
    half8 v;
#pragma unroll
    for (int j = 0; j < 8; j++) v[j] = (_Float16)0.f;
    return v;
}

// ---- convert 4 fp32 weight mats -> fp16 (contiguous dsts); zero S2 -------
__global__ void cvt4_kernel(const float* __restrict__ a, const float* __restrict__ b,
                            const float* __restrict__ c, const float* __restrict__ d,
                            _Float16* __restrict__ o, float* __restrict__ S2) {
    if (blockIdx.x == 0 && blockIdx.y == 0 && threadIdx.x < 32) S2[threadIdx.x] = 0.f;
    int y = blockIdx.y;
    const float* s = (y == 0) ? a : (y == 1) ? b : (y == 2) ? c : d;
    int i = blockIdx.x * 256 + threadIdx.x;
    o[(size_t)y * 262144 + i] = (_Float16)s[i];
}

// ---- x (B,C,H*W) -> xf16 (B, NQ, C) fp16 (tiled transpose) ---------------
__global__ void xpose_kernel(const float* __restrict__ x, _Float16* __restrict__ xf) {
    __shared__ float t[32][33];
    int n0 = blockIdx.x * 32, c0 = blockIdx.y * 32, b = blockIdx.z;
    int tx = threadIdx.x, ty = threadIdx.y;
#pragma unroll
    for (int i = 0; i < 4; i++)
        t[ty + 8 * i][tx] = x[((size_t)(b * CC) + c0 + ty + 8 * i) * NQ + n0 + tx];
    __syncthreads();
#pragma unroll
    for (int i = 0; i < 4; i++)
        xf[((size_t)(b * NQ) + n0 + ty + 8 * i) * CC + c0 + tx] = (_Float16)t[tx][ty + 8 * i];
}

// ---- depthwise conv 3x3 s2 p1 + bias -> xsc (B, OQ, C) fp32 --------------
__global__ void dw_kernel(const float* __restrict__ x, const float* __restrict__ w,
                          const float* __restrict__ bias, float* __restrict__ xsc) {
    int cb = blockIdx.x, oy = blockIdx.y, b = blockIdx.z;
    int tx = threadIdx.x, ty = threadIdx.y;
    int c = cb * 16 + ty;
    float a = bias[c];
    const float* xp = x + ((size_t)(b * CC + c) * HH) * WW;
#pragma unroll
    for (int ky = 0; ky < 3; ky++) {
        int iy = 2 * oy - 1 + ky;
        if (iy < 0 || iy >= HH) continue;
#pragma unroll
        for (int kx = 0; kx < 3; kx++) {
            int ix = 2 * tx - 1 + kx;
            if (ix < 0 || ix >= WW) continue;
            a += xp[iy * WW + ix] * w[c * 9 + ky * 3 + kx];
        }
    }
    __shared__ float tile[28][17];
    tile[tx][ty] = a;
    __syncthreads();
    int lin = ty * 28 + tx;
    int oi = lin >> 4, ci = lin & 15;
    xsc[((size_t)(b * OQ) + oy * 28 + oi) * CC + cb * 16 + ci] = tile[oi][ci];
}

// ---- LayerNorm over C -> xs16 (B*OQ, C) fp16 -----------------------------
__global__ __launch_bounds__(256) void ln_kernel(const float* __restrict__ xsc,
        const float* __restrict__ g, const float* __restrict__ bb,
        _Float16* __restrict__ xs16) {
    int row = blockIdx.x;
    const float* rp = xsc + (size_t)row * CC;
    int t = threadIdx.x;
    float v0 = rp[t], v1 = rp[t + 256];
    float s = v0 + v1, ss = v0 * v0 + v1 * v1;
#pragma unroll
    for (int m = 1; m < 64; m <<= 1) {
        s += __shfl_xor(s, m, 64);
        ss += __shfl_xor(ss, m, 64);
    }
    __shared__ float red[8];
    int wv = t >> 6;
    if ((t & 63) == 0) { red[wv] = s; red[4 + wv] = ss; }
    __syncthreads();
    s = red[0] + red[1] + red[2] + red[3];
    ss = red[4] + red[5] + red[6] + red[7];
    float mean = s * (1.f / 512.f);
    float var = ss * (1.f / 512.f) - mean * mean;
    float rs = rsqrtf(var + 1e-5f);
    xs16[(size_t)row * CC + t] = (_Float16)((v0 - mean) * rs * g[t] + bb[t]);
    xs16[(size_t)row * CC + t + 256] = (_Float16)((v1 - mean) * rs * g[t + 256] + bb[t + 256]);
}

// ---- fused q/k/v projections, 64x64 tiles, K=512 NT ----------------------
// grid (196, 8, 3): z=0 q (M=12544, A=xf16), z=1 k, z=2 v (M=3136, A=xs16)
__global__ __launch_bounds__(256) void gemm_qkv(const _Float16* __restrict__ xf,
        const _Float16* __restrict__ xs, const _Float16* __restrict__ w4,
        _Float16* __restrict__ q16, _Float16* __restrict__ k16, _Float16* __restrict__ vT) {
    const int which = blockIdx.z;
    if (which && blockIdx.x >= 49) return;
    const _Float16* A = which ? xs : xf;
    const _Float16* Bw = w4 + (size_t)which * 262144;
    __shared__ _Float16 As[64 * 72];
    __shared__ _Float16 Bs[64 * 72];
    const int m0 = blockIdx.x * 64, n0 = blockIdx.y * 64;
    const int tid = threadIdx.x;
    const int lane = tid & 63, wv = tid >> 6;
    const int wm = (wv >> 1) * 32, wn = (wv & 1) * 32;
    const int l15 = lane & 15, quad = lane >> 4;
    fx4 acc[2][2];
#pragma unroll
    for (int i = 0; i < 2; i++)
#pragma unroll
        for (int j = 0; j < 2; j++) acc[i][j] = fx4{0.f, 0.f, 0.f, 0.f};
    for (int k0 = 0; k0 < 512; k0 += 64) {
        __syncthreads();
#pragma unroll
        for (int i = 0; i < 2; i++) {
            int id = tid + 256 * i;
            int r = id >> 3, kc = (id & 7) << 3;
            *(half8*)(As + r * 72 + kc) = *(const half8*)(A + (size_t)(m0 + r) * 512 + k0 + kc);
            *(half8*)(Bs + r * 72 + kc) = *(const half8*)(Bw + (size_t)(n0 + r) * 512 + k0 + kc);
        }
        __syncthreads();
#pragma unroll
        for (int ks = 0; ks < 2; ks++) {
            half8 af[2], bf[2];
#pragma unroll
            for (int s = 0; s < 2; s++) {
                af[s] = *(const half8*)(As + (wm + s * 16 + l15) * 72 + ks * 32 + quad * 8);
                bf[s] = *(const half8*)(Bs + (wn + s * 16 + l15) * 72 + ks * 32 + quad * 8);
            }
#pragma unroll
            for (int i = 0; i < 2; i++)
#pragma unroll
                for (int j = 0; j < 2; j++)
                    acc[i][j] = MFMA16(af[i], bf[j], acc[i][j]);
        }
    }
    if (which < 2) {
        _Float16* O = which ? k16 : q16;
#pragma unroll
        for (int i = 0; i < 2; i++)
#pragma unroll
            for (int j = 0; j < 2; j++) {
                int col = n0 + wn + j * 16 + l15;
#pragma unroll
                for (int e = 0; e < 4; e++) {
                    int row = m0 + wm + i * 16 + quad * 4 + e;
                    O[(size_t)row * 512 + col] = (_Float16)acc[i][j][e];
                }
            }
    } else {
        // vT[(b*8 + c/64)*64 + c%64][o]; 4 consecutive o -> packed 8B store
#pragma unroll
        for (int i = 0; i < 2; i++) {
            int row = m0 + wm + i * 16 + quad * 4;  // b*784 + o, multiple of 4
            int b = row / OQ;
            int o = row - b * OQ;
#pragma unroll
            for (int j = 0; j < 2; j++) {
                int c = n0 + wn + j * 16 + l15;
                half4 pk;
#pragma unroll
                for (int e = 0; e < 4; e++) pk[e] = (_Float16)acc[i][j][e];
                *(half4*)(vT + ((size_t)(b * NH + (c >> 6)) * HD + (c & 63)) * OQ + o) = pk;
            }
        }
    }
}

// ---- QK^T + head-mix + logit write + partial Z / sum(E^2) ----------------
// grid (49 nblk, 7 oseg, 4 b), block 256 (4 waves, each a 16-row n-subtile)
__global__ __launch_bounds__(256) void qk_mix(const _Float16* __restrict__ q16,
        const _Float16* __restrict__ k16, const float* __restrict__ tcw,
        const float* __restrict__ tcb, _Float16* __restrict__ L,
        float* __restrict__ Zpart, float* __restrict__ E2part) {
    __shared__ _Float16 kl[16 * 520];
    __shared__ float tcs[64];
    __shared__ float tbb[8];
    const int b = blockIdx.z, oseg = blockIdx.y, ob = oseg * 112;
    const int tid = threadIdx.x;
    const int wv = tid >> 6, lane = tid & 63, l15 = lane & 15, quad = lane >> 4;
    const int n0 = blockIdx.x * 64 + wv * 16;
    if (tid < 64) tcs[tid] = tcw[tid] * 0.125f;  // fold scale hd^-0.5
    else if (tid < 72) tbb[tid - 64] = tcb[tid - 64];

    half8 aF[8][2];
    const _Float16* qrow = q16 + ((size_t)(b * NQ + n0 + l15)) * 512;
#pragma unroll
    for (int h = 0; h < 8; h++)
#pragma unroll
        for (int ks = 0; ks < 2; ks++)
            aF[h][ks] = *(const half8*)(qrow + h * 64 + ks * 32 + quad * 8);

    float z[8][4], s2[8][4];
#pragma unroll
    for (int g = 0; g < 8; g++)
#pragma unroll
        for (int e = 0; e < 4; e++) { z[g][e] = 0.f; s2[g][e] = 0.f; }

    for (int ot = 0; ot < 7; ot++) {
        int o0 = ob + ot * 16;
        __syncthreads();  // prior compute done before restage (also covers tcs init)
        const _Float16* kb = k16 + ((size_t)(b * OQ + o0)) * 512;
#pragma unroll
        for (int i = 0; i < 4; i++) {
            int id = tid + 256 * i;  // 1024 chunks of 8 halfs
            int r = id >> 6, c = (id & 63) << 3;
            *(half8*)(kl + r * 520 + c) = *(const half8*)(kb + (size_t)r * 512 + c);
        }
        __syncthreads();
        fx4 s[8];
#pragma unroll
        for (int h = 0; h < 8; h++) {
            fx4 a = fx4{0.f, 0.f, 0.f, 0.f};
#pragma unroll
            for (int ks = 0; ks < 2; ks++) {
                half8 bF = *(const half8*)(kl + l15 * 520 + h * 64 + ks * 32 + quad * 8);
                a = MFMA16(aF[h][ks], bF, a);
            }
            s[h] = a;
        }
#pragma unroll
        for (int g = 0; g < 8; g++) {
#pragma unroll
            for (int e = 0; e < 4; e++) {
                float v = tbb[g];
#pragma unroll
                for (int h = 0; h < 8; h++) v += tcs[g * 8 + h] * s[h][e];
                _Float16 vh = (_Float16)v;
                float vr = (float)vh;  // rounded value so Z matches pass 2 exactly
                float ex = __expf(vr);
                z[g][e] += ex;
                s2[g][e] += ex * ex;
                L[((size_t)((b * 8 + g) * NQ) + n0 + quad * 4 + e) * OQ + o0 + l15] = vh;
            }
        }
    }
#pragma unroll
    for (int m = 1; m < 16; m <<= 1) {
#pragma unroll
        for (int g = 0; g < 8; g++)
#pragma unroll
            for (int e = 0; e < 4; e++) {
                z[g][e] += __shfl_xor(z[g][e], m, 64);
                s2[g][e] += __shfl_xor(s2[g][e], m, 64);
            }
    }
    if (l15 < 8) {
        int g = l15;
        size_t base = (size_t)oseg * BGN + (size_t)(b * 8 + g) * NQ + n0 + quad * 4;
#pragma unroll
        for (int e = 0; e < 4; e++) {
            Zpart[base + e] = z[g][e];
            E2part[base + e] = s2[g][e];
        }
    }
}

// ---- sum partials: Zinv per row, S2[b,g] global --------------------------
__global__ __launch_bounds__(256) void zfin_kernel(const float* __restrict__ Zpart,
        const float* __restrict__ E2part, float* __restrict__ Zinv, float* __restrict__ S2) {
    int i = blockIdx.x * 256 + threadIdx.x;  // 0..BGN-1
    float z = 0.f, e2 = 0.f;
#pragma unroll
    for (int s = 0; s < NSEG; s++) {
        z += Zpart[(size_t)s * BGN + i];
        e2 += E2part[(size_t)s * BGN + i];
    }
    float zi = 1.f / z;
    Zinv[i] = zi;
    float r = e2 * zi * zi;
#pragma unroll
    for (int m = 1; m < 64; m <<= 1) r += __shfl_xor(r, m, 64);
    if ((threadIdx.x & 63) == 0) atomicAdd(&S2[i / NQ], r);
}

// ---- pass 2: softmax-normalize + instnorm + *W + PV ----------------------
// grid (196 nblk, 8 g, 4 b), block 64
__global__ __launch_bounds__(64) void pv_kernel(const _Float16* __restrict__ L,
        const float* __restrict__ W, const _Float16* __restrict__ vT,
        const float* __restrict__ Zinv, const float* __restrict__ S2,
        _Float16* __restrict__ outp) {
    const int b = blockIdx.z, n0 = blockIdx.x * 16, g = blockIdx.y;
    const int lane = threadIdx.x, l15 = lane & 15, quad = lane >> 4;
    const int bg = b * 8 + g;
    const float mm = 1.f / (float)OQ;
    float rv = rsqrtf(S2[bg] * (1.f / ((float)NQ * (float)OQ)) - mm * mm + 1e-5f);
    const float czr = Zinv[bg * NQ + n0 + l15] * rv;
    const float rm = rv * mm;
    const _Float16* Lrow = L + ((size_t)bg * NQ + n0 + l15) * OQ;
    const float* Wrow = W + ((size_t)bg * NQ + n0 + l15) * OQ;
    const _Float16* vb = vT + (size_t)bg * HD * OQ;
    fx4 acc[4];
#pragma unroll
    for (int d = 0; d < 4; d++) acc[d] = fx4{0.f, 0.f, 0.f, 0.f};

#pragma unroll 5
    for (int oc = 0; oc < 25; oc++) {
        int kbase = oc * 32 + quad * 8;
        bool valid = kbase < OQ;  // 784 = 24*32+16: tail chunk quads 2,3 off
        half8 aH = h8z();
        if (valid) {
            half8 l8 = *(const half8*)(Lrow + kbase);
            fx4 w0 = *(const fx4*)(Wrow + kbase);
            fx4 w1 = *(const fx4*)(Wrow + kbase + 4);
#pragma unroll
            for (int j = 0; j < 8; j++) {
                float e = __expf((float)l8[j]);
                float a = e * czr - rm;
                float wv = (j < 4) ? w0[j] : w1[j - 4];
                aH[j] = (_Float16)(a * wv);
            }
        }
#pragma unroll
        for (int ds = 0; ds < 4; ds++) {
            half8 bF = h8z();
            if (valid)
                bF = *(const half8*)(vb + ((size_t)(ds * 16 + l15)) * OQ + kbase);
            acc[ds] = MFMA16(aH, bF, acc[ds]);
        }
    }
#pragma unroll
    for (int ds = 0; ds < 4; ds++)
#pragma unroll
        for (int e = 0; e < 4; e++) {
            int n = n0 + quad * 4 + e;
            int c = g * 64 + ds * 16 + l15;
            outp[((size_t)b * NQ + n) * 512 + c] = (_Float16)acc[ds][e];
        }
}

// ---- proj GEMM 64x64 tiles: M=512 channels, N=3136 per b, bias, fp32 out -
__global__ __launch_bounds__(256) void gemm_proj(const _Float16* __restrict__ A,
        const _Float16* __restrict__ Ball, const float* __restrict__ bias,
        float* __restrict__ Oall) {
    __shared__ _Float16 As[64 * 72];
    __shared__ _Float16 Bs[64 * 72];
    const int b = blockIdx.z;
    const _Float16* Bm = Ball + (size_t)b * NQ * 512;
    float* O = Oall + (size_t)b * CC * NQ;
    const int m0 = blockIdx.x * 64, n0 = blockIdx.y * 64;
    const int tid = threadIdx.x;
    const int lane = tid & 63, wv = tid >> 6;
    const int wm = (wv >> 1) * 32, wn = (wv & 1) * 32;
    const int l15 = lane & 15, quad = lane >> 4;
    fx4 acc[2][2];
#pragma unroll
    for (int i = 0; i < 2; i++)
#pragma unroll
        for (int j = 0; j < 2; j++) acc[i][j] = fx4{0.f, 0.f, 0.f, 0.f};
    for (int k0 = 0; k0 < 512; k0 += 64) {
        __syncthreads();
#pragma unroll
        for (int i = 0; i < 2; i++) {
            int id = tid + 256 * i;
            int r = id >> 3, kc = (id & 7) << 3;
            *(half8*)(As + r * 72 + kc) = *(const half8*)(A + (size_t)(m0 + r) * 512 + k0 + kc);
            *(half8*)(Bs + r * 72 + kc) = *(const half8*)(Bm + (size_t)(n0 + r) * 512 + k0 + kc);
        }
        __syncthreads();
#pragma unroll
        for (int ks = 0; ks < 2; ks++) {
            half8 af[2], bf[2];
#pragma unroll
            for (int s = 0; s < 2; s++) {
                af[s] = *(const half8*)(As + (wm + s * 16 + l15) * 72 + ks * 32 + quad * 8);
                bf[s] = *(const half8*)(Bs + (wn + s * 16 + l15) * 72 + ks * 32 + quad * 8);
            }
#pragma unroll
            for (int i = 0; i < 2; i++)
#pragma unroll
                for (int j = 0; j < 2; j++)
                    acc[i][j] = MFMA16(af[i], bf[j], acc[i][j]);
        }
    }
#pragma unroll
    for (int i = 0; i < 2; i++)
#pragma unroll
        for (int j = 0; j < 2; j++) {
            int col = n0 + wn + j * 16 + l15;
#pragma unroll
            for (int e = 0; e < 4; e++) {
                int row = m0 + wm + i * 16 + quad * 4 + e;
                O[(size_t)row * NQ + col] = acc[i][j][e] + bias[row];
            }
        }
}

extern "C" void kernel_launch(void* const* d_in, const int* in_sizes, int n_in,
                              void* d_out, int out_size, void* d_ws, size_t ws_size,
                              hipStream_t stream) {
    const float* x = (const float*)d_in[0];
    const float* aw = (const float*)d_in[1];
    const float* q_w = (const float*)d_in[2];
    const float* k_w = (const float*)d_in[3];
    const float* v_w = (const float*)d_in[4];
    const float* sr_w = (const float*)d_in[5];
    const float* sr_b = (const float*)d_in[6];
    const float* ln_g = (const float*)d_in[7];
    const float* ln_b = (const float*)d_in[8];
    const float* tc_w = (const float*)d_in[9];
    const float* tc_b = (const float*)d_in[10];
    const float* p_w = (const float*)d_in[11];
    const float* p_b = (const float*)d_in[12];
    float* out = (float*)d_out;

    char* p = (char*)d_ws;
    auto take = [&](size_t bytes) -> char* {
        char* r = p;
        p += (bytes + 255) & ~(size_t)255;
        return r;
    };
    _Float16* qw16 = (_Float16*)take(512 * 512 * 2);  // qw,kw,vw,pw contiguous
    _Float16* kw16 = (_Float16*)take(512 * 512 * 2);
    _Float16* vw16 = (_Float16*)take(512 * 512 * 2);
    _Float16* pw16 = (_Float16*)take(512 * 512 * 2);
    _Float16* xf16 = (_Float16*)take((size_t)BN * NQ * CC * 2);
    float* xsc = (float*)take((size_t)BN * OQ * CC * 4);
    _Float16* xs16 = (_Float16*)take((size_t)BN * OQ * CC * 2);
    _Float16* q16 = (_Float16*)take((size_t)BN * NQ * CC * 2);
    _Float16* k16 = (_Float16*)take((size_t)BN * OQ * CC * 2);
    _Float16* vT = (_Float16*)take((size_t)BN * OQ * CC * 2);
    _Float16* outp = (_Float16*)take((size_t)BN * NQ * CC * 2);
    float* Zpart = (float*)take((size_t)NSEG * BGN * 4);
    float* E2part = (float*)take((size_t)NSEG * BGN * 4);
    float* S2 = (float*)take(32 * 4);
    float* Zinv = (float*)take((size_t)BGN * 4);
    _Float16* L = (_Float16*)take((size_t)BN * NH * NQ * OQ * 2);

    // weights to fp16 (S2 zeroed here too)
    cvt4_kernel<<<dim3(1024, 4), 256, 0, stream>>>(q_w, k_w, v_w, p_w, qw16, S2);
    // x transpose to (B,NQ,C) fp16
    xpose_kernel<<<dim3(98, 16, BN), dim3(32, 8), 0, stream>>>(x, xf16);
    // spatial reduction conv + LN
    dw_kernel<<<dim3(32, 28, BN), dim3(28, 16), 0, stream>>>(x, sr_w, sr_b, xsc);
    ln_kernel<<<BN * OQ, 256, 0, stream>>>(xsc, ln_g, ln_b, xs16);
    // fused q/k/v projections (v written directly as vT)
    gemm_qkv<<<dim3(196, 8, 3), 256, 0, stream>>>(xf16, xs16, qw16, q16, k16, vT);
    // phase 1: logits + partial softmax stats (4-wave blocks, no atomics)
    qk_mix<<<dim3(49, 7, BN), 256, 0, stream>>>(q16, k16, tc_w, tc_b, L, Zpart, E2part);
    zfin_kernel<<<BGN / 256, 256, 0, stream>>>(Zpart, E2part, Zinv, S2);
    // phase 2: normalize + instnorm + attn_weights + PV (R computed inline)
    pv_kernel<<<dim3(196, 8, BN), 64, 0, stream>>>(L, aw, vT, Zinv, S2, outp);
    // output projection + bias, written directly in (B,C,H,W)
    gemm_proj<<<dim3(8, 49, BN), 256, 0, stream>>>(pw16, outp, p_b, out);
}